// Round 12
// baseline (217.185 us; speedup 1.0000x reference)
//
#include <hip/hip_runtime.h>
#include <math.h>

#define NTOK 2304      // 48*48 tokens
#define BATCH 2
#define CIN 256
#define HID 512        // 8 heads * 64
#define NH 8
#define LOG2E 1.44269504088896340736f

typedef __attribute__((ext_vector_type(8))) short bfrag;    // 8 bf16 (4 VGPRs)
typedef __attribute__((ext_vector_type(16))) float f32x16;  // MFMA 32x32 accumulator

#if __has_builtin(__builtin_amdgcn_exp2f)
#define EXP2(x) __builtin_amdgcn_exp2f(x)
#else
#define EXP2(x) exp2f(x)
#endif

// fp32 -> bf16 (RNE)
__device__ __forceinline__ unsigned f2bf(float f) {
    unsigned u = __float_as_uint(f);
    u += 0x7FFF + ((u >> 16) & 1);
    return u >> 16;
}

// pack trunc(hi(b)) , trunc(hi(a)) -> one dword {bf16(b):bf16(a)} in 1 v_perm
__device__ __forceinline__ unsigned pk_trunc(float a, float b) {
    return __builtin_amdgcn_perm(__float_as_uint(b), __float_as_uint(a), 0x07060302u);
}

// exp2 + bf16-pack + lane^32 half-swap: accS (S^T quadrant, C-layout) ->
// two A-operand P frags; accumulates this lane's partial row sums.
__device__ __forceinline__ void softmax_frag(
    const f32x16& accS, int h, float& ps0, float& ps1, bfrag& P0, bfrag& P1)
{
    unsigned dw[8];
#pragma unroll
    for (int i = 0; i < 8; i++) {
        float plo = EXP2(accS[2 * i]);
        float phi = EXP2(accS[2 * i + 1]);
        dw[i] = pk_trunc(plo, phi);
        ps0 += __uint_as_float(dw[i] << 16);
        ps1 += __uint_as_float(dw[i] & 0xffff0000u);
    }
    unsigned sa0 = h ? dw[0] : dw[2], sb0 = h ? dw[1] : dw[3];
    unsigned sa1 = h ? dw[4] : dw[6], sb1 = h ? dw[5] : dw[7];
    unsigned ra0 = (unsigned)__shfl_xor((int)sa0, 32, 64);
    unsigned rb0 = (unsigned)__shfl_xor((int)sb0, 32, 64);
    unsigned ra1 = (unsigned)__shfl_xor((int)sa1, 32, 64);
    unsigned rb1 = (unsigned)__shfl_xor((int)sb1, 32, 64);
    union { bfrag f; unsigned u[4]; } U0, U1;
    U0.u[0] = h ? ra0 : dw[0];  U0.u[1] = h ? rb0 : dw[1];
    U0.u[2] = h ? dw[2] : ra0;  U0.u[3] = h ? dw[3] : rb0;
    U1.u[0] = h ? ra1 : dw[4];  U1.u[1] = h ? rb1 : dw[5];
    U1.u[2] = h ? dw[6] : ra1;  U1.u[3] = h ? dw[7] : rb1;
    P0 = U0.f; P1 = U1.f;
}

// ---------------------------------------------------------------------------
// Fused input pack: blocks [0,256) pack both weight matrices elementwise;
// blocks [256,544) transpose-pack x fp32 [b][256][2304] -> bf16 xT [b][n][256].
// ---------------------------------------------------------------------------
__global__ __launch_bounds__(256) void pack_inputs(
    const float* __restrict__ wq, short* __restrict__ wqb,
    const float* __restrict__ wp, short* __restrict__ wpb,
    const float* __restrict__ x, short* __restrict__ xT)
{
    int bid = blockIdx.x;
    int tid = threadIdx.x;
    if (bid < 256) {
        int e = (bid * 256 + tid) * 8;
        const int NQ = 1536 * 256;
        const float* src; short* dst;
        if (e < NQ) { src = wq + e; dst = wqb + e; }
        else        { src = wp + (e - NQ); dst = wpb + (e - NQ); }
        float4 v0 = ((const float4*)src)[0];
        float4 v1 = ((const float4*)src)[1];
        unsigned b0 = f2bf(v0.x) | (f2bf(v0.y) << 16);
        unsigned b1 = f2bf(v0.z) | (f2bf(v0.w) << 16);
        unsigned b2 = f2bf(v1.x) | (f2bf(v1.y) << 16);
        unsigned b3 = f2bf(v1.z) | (f2bf(v1.w) << 16);
        *((uint4*)dst) = make_uint4(b0, b1, b2, b3);
        return;
    }
    int idx = bid - 256;                 // 288 transpose tiles
    int n0 = (idx % 36) * 64;
    int c0 = ((idx / 36) & 3) * 64;
    int b = idx / 144;
    __shared__ float sT[64][65];
    int lane = tid & 63, wv = tid >> 6;
    for (int c = wv; c < 64; c += 4)
        sT[c][lane] = x[((size_t)b * CIN + c0 + c) * NTOK + n0 + lane];
    __syncthreads();
    int n = tid >> 2, c4 = (tid & 3) * 16;
    unsigned buf[8];
#pragma unroll
    for (int i = 0; i < 8; i++)
        buf[i] = f2bf(sT[c4 + 2 * i][n]) | (f2bf(sT[c4 + 2 * i + 1][n]) << 16);
    short* dst = xT + ((size_t)b * NTOK + n0 + n) * CIN + c0 + c4;
    ((uint4*)dst)[0] = make_uint4(buf[0], buf[1], buf[2], buf[3]);
    ((uint4*)dst)[1] = make_uint4(buf[4], buf[5], buf[6], buf[7]);
}

// ---------------------------------------------------------------------------
// QKV GEMM (MFMA): BM=128, BN=128, K=256, grid (18, 12, 2).
// o<1024 (q,k): epilogue writes bf16 TOKEN-MAJOR qkt[sel][bh][n][64] via an
// in-block LDS pair-transpose (C-layout reg pair (2i,2i+1) = adjacent d at
// fixed n -> one dword), and accumulates per-(b,o)-row sum of squares into
// sqsum via shuffle-reduce + atomicAdd (for the fold-into-k normalization).
// o>=1024 (v): bf16 [b][512][NTOK] d-major, as before.
// ---------------------------------------------------------------------------
__global__ __launch_bounds__(256, 2) void gemm_qkv(
    const short* __restrict__ A, const short* __restrict__ B,
    short* __restrict__ qkt, short* __restrict__ vb,
    float* __restrict__ sqsum)
{
    const int K = CIN;
    int b = blockIdx.z;
    int o0 = blockIdx.y * 128;
    int n0 = blockIdx.x * 128;
    int tid = threadIdx.x, wv = tid >> 6, lane = tid & 63;
    int h = lane >> 5, l31 = lane & 31;

    __shared__ unsigned T[16][132];   // d-pair x n transpose staging (8.4 KB)

    const short* pa = A + (size_t)(o0 + l31) * K + h * 8;
    const short* pb = B + ((size_t)b * NTOK + n0 + wv * 32 + l31) * K + h * 8;

    f32x16 acc[4];
#pragma unroll
    for (int rb = 0; rb < 4; rb++)
#pragma unroll
        for (int r = 0; r < 16; r++) acc[rb][r] = 0.f;

#pragma unroll 2
    for (int kt = 0; kt < K; kt += 16) {
        bfrag a0 = *(const bfrag*)(pa + kt);
        bfrag a1 = *(const bfrag*)(pa + (size_t)32 * K + kt);
        bfrag a2 = *(const bfrag*)(pa + (size_t)64 * K + kt);
        bfrag a3 = *(const bfrag*)(pa + (size_t)96 * K + kt);
        bfrag bb = *(const bfrag*)(pb + kt);
        acc[0] = __builtin_amdgcn_mfma_f32_32x32x16_bf16(a0, bb, acc[0], 0, 0, 0);
        acc[1] = __builtin_amdgcn_mfma_f32_32x32x16_bf16(a1, bb, acc[1], 0, 0, 0);
        acc[2] = __builtin_amdgcn_mfma_f32_32x32x16_bf16(a2, bb, acc[2], 0, 0, 0);
        acc[3] = __builtin_amdgcn_mfma_f32_32x32x16_bf16(a3, bb, acc[3], 0, 0, 0);
    }

    int nn_local = wv * 32 + l31;
    int nn = n0 + nn_local;

    if (o0 < 1024) {
        int sel = o0 >> 9;            // 0 = q, 1 = k (block never straddles)
#pragma unroll
        for (int rb = 0; rb < 4; rb++) {
            int o_rb = o0 + 32 * rb;
            int head = (o_rb & 511) >> 6;
            int dbase = o_rb & 32;    // 0 or 32 within the head
            // --- per-row sum of squares -> atomicAdd
#pragma unroll
            for (int r = 0; r < 16; r++) {
                float v = acc[rb][r] * acc[rb][r];
                v += __shfl_xor(v, 1, 64);
                v += __shfl_xor(v, 2, 64);
                v += __shfl_xor(v, 4, 64);
                v += __shfl_xor(v, 8, 64);
                v += __shfl_xor(v, 16, 64);
                if (l31 == 0) {
                    int row = (r & 3) + 8 * (r >> 2) + 4 * h;
                    atomicAdd(&sqsum[b * 1024 + o_rb + row], v);
                }
            }
            // --- bf16 pair-pack + LDS transpose to token-major
#pragma unroll
            for (int i = 0; i < 8; i++) {
                unsigned dwp = f2bf(acc[rb][2 * i]) | (f2bf(acc[rb][2 * i + 1]) << 16);
                int pair = (((2 * i) & 3) + 8 * ((2 * i) >> 2) + 4 * h) >> 1;
                T[pair][nn_local] = dwp;
            }
            __syncthreads();
            {
                int n = tid >> 1, hf = tid & 1;
                unsigned o8[8];
#pragma unroll
                for (int j = 0; j < 8; j++) o8[j] = T[hf * 8 + j][n];
                short* dst = qkt + (size_t)sel * ((size_t)16 * NTOK * 64)
                           + ((size_t)(b * 8 + head) * NTOK + n0 + n) * 64
                           + dbase + hf * 16;
                ((uint4*)dst)[0] = make_uint4(o8[0], o8[1], o8[2], o8[3]);
                ((uint4*)dst)[1] = make_uint4(o8[4], o8[5], o8[6], o8[7]);
            }
            __syncthreads();
        }
    } else {
        short* V = vb + (size_t)b * 512 * NTOK;
        int ov = o0 - 1024;
#pragma unroll
        for (int rb = 0; rb < 4; rb++)
#pragma unroll
            for (int r = 0; r < 16; r++) {
                int ml = (r & 3) + 8 * (r >> 2) + 4 * h;
                V[(size_t)(ov + rb * 32 + ml) * NTOK + nn] = (short)f2bf(acc[rb][r]);
            }
    }
}

// ---------------------------------------------------------------------------
// Scale k in place: k~[d,m] = k[d,m] * LOG2E / (max(|q_d|,eps)*max(|k_d|,eps)).
// qkt k-half is [bh][n][64]; block = 2048 elems = 32 n-rows of one bh.
// grid 1152. Folds BOTH L2 norms and log2(e) into K (q stays raw bf16).
// ---------------------------------------------------------------------------
__global__ __launch_bounds__(256) void scale_k(
    short* __restrict__ qkt, const float* __restrict__ sqsum)
{
    __shared__ float s[64];
    short* kbase = qkt + (size_t)16 * NTOK * 64;
    size_t e0 = (size_t)blockIdx.x * 2048;
    int bh = (int)(e0 / ((size_t)NTOK * 64));
    int b = bh >> 3, head = bh & 7;
    int tid = threadIdx.x;
    if (tid < 64) {
        float nq = sqrtf(sqsum[b * 1024 + head * 64 + tid]);
        float nk = sqrtf(sqsum[b * 1024 + 512 + head * 64 + tid]);
        s[tid] = LOG2E / (fmaxf(nq, 1e-12f) * fmaxf(nk, 1e-12f));
    }
    __syncthreads();

    size_t e = e0 + (size_t)tid * 8;
    int d0 = (int)(e & 63);
    uint4 u = *(const uint4*)(kbase + e);
    unsigned w[4] = { u.x, u.y, u.z, u.w };
    unsigned o[4];
#pragma unroll
    for (int i = 0; i < 4; i++) {
        float lo = __uint_as_float(w[i] << 16) * s[d0 + 2 * i];
        float hi = __uint_as_float(w[i] & 0xffff0000u) * s[d0 + 2 * i + 1];
        o[i] = f2bf(lo) | (f2bf(hi) << 16);
    }
    *(uint4*)(kbase + e) = make_uint4(o[0], o[1], o[2], o[3]);
}

// ---------------------------------------------------------------------------
// Barrier-free attention (R7 verbatim — best measured at 74.8 us).
// 1-D grid 288: g = bid & 31 -> (bh, ms); ntile = bid >> 5.
// Sharers of one (bh,ms) K/V-set differ by 32 (= 0 mod 8) -> same XCD ->
// K/V L2-resident. Wave owns two 32-n groups sharing the K/V loads.
// 8 batched loads at iter top; VGPR ~124 keeps them in flight.
// ---------------------------------------------------------------------------
__global__ __launch_bounds__(256, 2) void attn_nb(
    const short* __restrict__ qkt,   // [2][16][2304][64] bf16 (k pre-scaled)
    const short* __restrict__ vb,    // [2][512][2304] bf16
    float* __restrict__ Opart,       // [2 split][2][2304][512] fp32
    float* __restrict__ lsum)        // [2 split][16][2304] fp32
{
    int bid = blockIdx.x;
    int g = bid & 31;
    int bh = g >> 1, ms = g & 1;
    int ntile = bid >> 5;
    int b = bh >> 3, hh = bh & 7;
    int tid = threadIdx.x, wv = tid >> 6, lane = tid & 63;
    int h = lane >> 5, l31 = lane & 31;
    int nb0 = ntile * 256 + wv * 32;
    int nb1 = nb0 + 128;
    int mbase = ms * (NTOK / 2);

    const short* Qt = qkt + (size_t)bh * NTOK * 64;
    const short* kp = qkt + (size_t)16 * NTOK * 64
                    + ((size_t)bh * NTOK + mbase + l31) * 64 + h * 8;
    const short* vl = vb + ((size_t)b * 512 + hh * 64 + l31) * NTOK + mbase + h * 8;
    const short* vh2 = vl + (size_t)32 * NTOK;

    bfrag bQ0[4], bQ1[4];
    {
        const short* q0 = Qt + (size_t)(nb0 + l31) * 64 + h * 8;
        const short* q1 = Qt + (size_t)(nb1 + l31) * 64 + h * 8;
#pragma unroll
        for (int i = 0; i < 4; i++) {
            bQ0[i] = *(const bfrag*)(q0 + i * 16);
            bQ1[i] = *(const bfrag*)(q1 + i * 16);
        }
    }

    f32x16 aL0, aH0, aL1, aH1;
#pragma unroll
    for (int r = 0; r < 16; r++) { aL0[r] = 0.f; aH0[r] = 0.f; aL1[r] = 0.f; aH1[r] = 0.f; }
    float s00 = 0.f, s01 = 0.f, s10 = 0.f, s11 = 0.f;

#pragma unroll 2
    for (int it = 0; it < 36; it++) {
        bfrag k0 = *(const bfrag*)(kp);
        bfrag k1 = *(const bfrag*)(kp + 16);
        bfrag k2 = *(const bfrag*)(kp + 32);
        bfrag k3 = *(const bfrag*)(kp + 48);
        bfrag v00 = *(const bfrag*)(vl);
        bfrag v01 = *(const bfrag*)(vl + 16);
        bfrag v10 = *(const bfrag*)(vh2);
        bfrag v11 = *(const bfrag*)(vh2 + 16);
        kp += 2048; vl += 32; vh2 += 32;

        bfrag P00, P01, P10, P11;
        {
            f32x16 accS;
#pragma unroll
            for (int r = 0; r < 16; r++) accS[r] = 0.f;
            accS = __builtin_amdgcn_mfma_f32_32x32x16_bf16(k0, bQ0[0], accS, 0, 0, 0);
            accS = __builtin_amdgcn_mfma_f32_32x32x16_bf16(k1, bQ0[1], accS, 0, 0, 0);
            accS = __builtin_amdgcn_mfma_f32_32x32x16_bf16(k2, bQ0[2], accS, 0, 0, 0);
            accS = __builtin_amdgcn_mfma_f32_32x32x16_bf16(k3, bQ0[3], accS, 0, 0, 0);
            softmax_frag(accS, h, s00, s01, P00, P01);
        }
        {
            f32x16 accS;
#pragma unroll
            for (int r = 0; r < 16; r++) accS[r] = 0.f;
            accS = __builtin_amdgcn_mfma_f32_32x32x16_bf16(k0, bQ1[0], accS, 0, 0, 0);
            accS = __builtin_amdgcn_mfma_f32_32x32x16_bf16(k1, bQ1[1], accS, 0, 0, 0);
            accS = __builtin_amdgcn_mfma_f32_32x32x16_bf16(k2, bQ1[2], accS, 0, 0, 0);
            accS = __builtin_amdgcn_mfma_f32_32x32x16_bf16(k3, bQ1[3], accS, 0, 0, 0);
            softmax_frag(accS, h, s10, s11, P10, P11);
        }
        aL0 = __builtin_amdgcn_mfma_f32_32x32x16_bf16(P00, v00, aL0, 0, 0, 0);
        aL0 = __builtin_amdgcn_mfma_f32_32x32x16_bf16(P01, v01, aL0, 0, 0, 0);
        aH0 = __builtin_amdgcn_mfma_f32_32x32x16_bf16(P00, v10, aH0, 0, 0, 0);
        aH0 = __builtin_amdgcn_mfma_f32_32x32x16_bf16(P01, v11, aH0, 0, 0, 0);
        aL1 = __builtin_amdgcn_mfma_f32_32x32x16_bf16(P10, v00, aL1, 0, 0, 0);
        aL1 = __builtin_amdgcn_mfma_f32_32x32x16_bf16(P11, v01, aL1, 0, 0, 0);
        aH1 = __builtin_amdgcn_mfma_f32_32x32x16_bf16(P10, v10, aH1, 0, 0, 0);
        aH1 = __builtin_amdgcn_mfma_f32_32x32x16_bf16(P11, v11, aH1, 0, 0, 0);
    }

    float p0 = s00 + s01;
    p0 += __shfl_xor(p0, 32, 64);
    float p1 = s10 + s11;
    p1 += __shfl_xor(p1, 32, 64);
    if (h == 0) {
        lsum[((size_t)ms * 16 + bh) * NTOK + nb0 + l31] = p0;
        lsum[((size_t)ms * 16 + bh) * NTOK + nb1 + l31] = p1;
    }

    float* Ob = Opart + (size_t)ms * (2ull * NTOK * HID)
              + (size_t)b * NTOK * HID + hh * 64;
#pragma unroll
    for (int r = 0; r < 16; r++) {
        int ml = (r & 3) + 8 * (r >> 2) + 4 * h;
        Ob[(size_t)(nb0 + ml) * HID + l31] = aL0[r];
        Ob[(size_t)(nb0 + ml) * HID + 32 + l31] = aH0[r];
        Ob[(size_t)(nb1 + ml) * HID + l31] = aL1[r];
        Ob[(size_t)(nb1 + ml) * HID + 32 + l31] = aH1[r];
    }
}

// ---------------------------------------------------------------------------
// Combine two m-splits, normalize, pack bf16 aoT [b][n][512]. 8 elems/thread.
// ---------------------------------------------------------------------------
__global__ __launch_bounds__(256) void combine(
    const float* __restrict__ Opart, const float* __restrict__ lsum,
    short* __restrict__ aoT)
{
    size_t e = ((size_t)blockIdx.x * 256 + threadIdx.x) * 8;
    int c = (int)(e & 511);
    size_t row = e >> 9;                 // b*2304 + n
    int b = (int)(row / NTOK), n = (int)(row - (size_t)b * NTOK);
    int hh = c >> 6;
    float l0 = lsum[(size_t)(b * 8 + hh) * NTOK + n];
    float l1 = lsum[(size_t)16 * NTOK + (size_t)(b * 8 + hh) * NTOK + n];
    float inv = 1.f / (l0 + l1);
    const float* P0 = Opart + e;
    const float* P1 = Opart + (size_t)2 * NTOK * HID + e;
    float4 a0 = ((const float4*)P0)[0], a1 = ((const float4*)P0)[1];
    float4 c0 = ((const float4*)P1)[0], c1 = ((const float4*)P1)[1];
    unsigned b0 = f2bf((a0.x + c0.x) * inv) | (f2bf((a0.y + c0.y) * inv) << 16);
    unsigned b1 = f2bf((a0.z + c0.z) * inv) | (f2bf((a0.w + c0.w) * inv) << 16);
    unsigned b2 = f2bf((a1.x + c1.x) * inv) | (f2bf((a1.y + c1.y) * inv) << 16);
    unsigned b3 = f2bf((a1.z + c1.z) * inv) | (f2bf((a1.w + c1.w) * inv) << 16);
    *((uint4*)(aoT + e)) = make_uint4(b0, b1, b2, b3);
}

// ---------------------------------------------------------------------------
// Proj GEMM (MFMA, direct store + bias). BM=64, BN=128, K=512.
// grid (18, 4, 2). unroll 4.
// ---------------------------------------------------------------------------
__global__ __launch_bounds__(256, 2) void gemm_proj(
    const short* __restrict__ A, const short* __restrict__ B,
    const float* __restrict__ bias, float* __restrict__ y)
{
    const int K = HID;
    int b = blockIdx.z;
    int o0 = blockIdx.y * 64;
    int n0 = blockIdx.x * 128;
    int tid = threadIdx.x, wv = tid >> 6, lane = tid & 63;
    int h = lane >> 5, l31 = lane & 31;

    const short* pa0 = A + (size_t)(o0 + l31) * K + h * 8;
    const short* pa1 = pa0 + (size_t)32 * K;
    const short* pb  = B + ((size_t)b * NTOK + n0 + wv * 32 + l31) * K + h * 8;

    f32x16 acc0, acc1;
#pragma unroll
    for (int r = 0; r < 16; r++) { acc0[r] = 0.f; acc1[r] = 0.f; }

#pragma unroll 4
    for (int kt = 0; kt < K; kt += 16) {
        bfrag a0 = *(const bfrag*)(pa0 + kt);
        bfrag a1 = *(const bfrag*)(pa1 + kt);
        bfrag bb = *(const bfrag*)(pb + kt);
        acc0 = __builtin_amdgcn_mfma_f32_32x32x16_bf16(a0, bb, acc0, 0, 0, 0);
        acc1 = __builtin_amdgcn_mfma_f32_32x32x16_bf16(a1, bb, acc1, 0, 0, 0);
    }

    int nn = n0 + wv * 32 + l31;
#pragma unroll
    for (int r = 0; r < 16; r++) {
        int ml = (r & 3) + 8 * (r >> 2) + 4 * h;
        y[((size_t)b * CIN + o0 + ml) * NTOK + nn] = acc0[r] + bias[o0 + ml];
        y[((size_t)b * CIN + o0 + 32 + ml) * NTOK + nn] = acc1[r] + bias[o0 + 32 + ml];
    }
}

// ---------------------------------------------------------------------------
// Workspace (<= 36,446,208 B of 37,748,736):
//   [0, 18,874,368)           Opart fp32 [2 split][2][2304][512] (k4 -> k5)
//   [18,874,368, 23,592,960)  vb bf16 [2][512][2304]     (k2 -> k4)
//   [23,592,960, 33,030,144)  qkt bf16 [2][16][2304][64] (k2 -> k4)
//       then aoT bf16 [2][2304][512]                     (k5 -> k6)
//   [33,030,144, 33,325,056)  lsum fp32 [2][16][2304]    (k4 -> k5, over dead xT)
//   [33,030,144, 35,389,440)  xT bf16                     (k1 -> k2, dead at k4)
//   [35,389,440, 36,175,872)  wqb bf16
//   [36,175,872, 36,438,016)  wpb bf16
//   [36,438,016, 36,446,208)  sqsum fp32 [2][1024] (memset 0, k2 atomics -> k3)
// ---------------------------------------------------------------------------
extern "C" void kernel_launch(void* const* d_in, const int* in_sizes, int n_in,
                              void* d_out, int out_size, void* d_ws, size_t ws_size,
                              hipStream_t stream)
{
    const float* x      = (const float*)d_in[0];
    const float* w_qkv  = (const float*)d_in[1];
    const float* w_proj = (const float*)d_in[2];
    const float* b_proj = (const float*)d_in[3];
    float* y = (float*)d_out;

    float* Opart = (float*)d_ws;
    short* vb    = (short*)((char*)d_ws + 18874368);
    short* qkt   = (short*)((char*)d_ws + 23592960);
    short* aoT   = (short*)((char*)d_ws + 23592960);
    float* lsum  = (float*)((char*)d_ws + 33030144);
    short* xT    = (short*)((char*)d_ws + 33030144);
    short* wqb   = (short*)((char*)d_ws + 35389440);
    short* wpb   = (short*)((char*)d_ws + 36175872);
    float* sqsum = (float*)((char*)d_ws + 36438016);

    // zero the sum-of-squares accumulator (8 KB)
    hipMemsetAsync(sqsum, 0, 2048 * sizeof(float), stream);

    // k1: pack weights + transpose-pack x
    pack_inputs<<<544, 256, 0, stream>>>(w_qkv, wqb, w_proj, wpb, x, xT);
    // k2: QKV GEMM -> q,k bf16 token-major (+row sq-sums), v bf16 d-major
    gemm_qkv<<<dim3(NTOK / 128, 1536 / 128, BATCH), 256, 0, stream>>>(
        wqb, xT, qkt, vb, sqsum);
    // k3: fold both L2 norms + log2e into k (in place)
    scale_k<<<1152, 256, 0, stream>>>(qkt, sqsum);
    // k4: attention — R7 verbatim (288 fat blocks, XCD swizzle)
    attn_nb<<<288, 256, 0, stream>>>(qkt, vb, Opart, lsum);
    // k5: combine splits -> aoT bf16 (over dead qkt)
    combine<<<(BATCH * NTOK * HID / 8) / 256, 256, 0, stream>>>(Opart, lsum, aoT);
    // k6: proj GEMM, direct store + bias
    gemm_proj<<<dim3(NTOK / 128, CIN / 64, BATCH), 256, 0, stream>>>(
        wpb, aoT, b_proj, y);
}